// Round 5
// baseline (21.426 us; speedup 1.0000x reference)
//
#include <hip/hip_runtime.h>
#include <math.h>

#define EPS 1e-6f
#define FLT_BIG 3.402823466e+38f

constexpr int BLK = 256;     // threads per block (k_min)
constexpr int MPT = 4;       // m's per thread (register blocking)
constexpr int NCHUNK = 32;   // l-chunks (grid.y of k_min)
constexpr int MAXCL = 256;   // LDS float4 capacity (4 KiB)
constexpr int RBLK = 1024;   // threads per block (k_reduce)

// Per (b, chunk): stage CL points of contour1 as (||p||^2, -2x, -2y, -2z),
// then each thread computes, for MPT m's, the chunk-partial
//   min_l(||p||^2 - 2 p.q) + ||q||^2   with q = c2[m] - eps,
// and writes it to part[b][chunk][m]. No atomics, fixed order.
__global__ void __launch_bounds__(BLK)
k_min(const float* __restrict__ c1, const float* __restrict__ c2,
      float* __restrict__ part, int L1, int L2, int CL) {
    __shared__ float4 tile[MAXCL];

    const int b = blockIdx.z;
    const int chunk = blockIdx.y;
    const int l0 = chunk * CL;
    const int nl = min(CL, L1 - l0);

    const float* src = c1 + ((size_t)b * L1 + l0) * 3;
    for (int i = threadIdx.x; i < nl; i += BLK) {
        float x = src[3 * i], y = src[3 * i + 1], z = src[3 * i + 2];
        tile[i] = make_float4(fmaf(x, x, fmaf(y, y, z * z)),
                              -2.0f * x, -2.0f * y, -2.0f * z);
    }
    __syncthreads();

    const int mbase = blockIdx.x * (BLK * MPT) + threadIdx.x;

    float q0[MPT], q1[MPT], q2[MPT], mn[MPT];
    #pragma unroll
    for (int j = 0; j < MPT; ++j) {
        const int m = mbase + j * BLK;
        if (m < L2) {
            const float* q = c2 + ((size_t)b * L2 + m) * 3;
            q0[j] = q[0] - EPS; q1[j] = q[1] - EPS; q2[j] = q[2] - EPS;
        } else {
            q0[j] = q1[j] = q2[j] = 0.0f;
        }
        mn[j] = FLT_BIG;
    }

    // 2 l's per iteration so fminf(mn, fminf(ta,tb)) can fuse to v_min3_f32.
    int l = 0;
    #pragma unroll 2
    for (; l + 2 <= nl; l += 2) {
        float4 pa = tile[l], pb = tile[l + 1];
        #pragma unroll
        for (int j = 0; j < MPT; ++j) {
            float ta = fmaf(pa.w, q2[j], fmaf(pa.z, q1[j], fmaf(pa.y, q0[j], pa.x)));
            float tb = fmaf(pb.w, q2[j], fmaf(pb.z, q1[j], fmaf(pb.y, q0[j], pb.x)));
            mn[j] = fminf(mn[j], fminf(ta, tb));
        }
    }
    for (; l < nl; ++l) {
        float4 p = tile[l];
        #pragma unroll
        for (int j = 0; j < MPT; ++j) {
            float t = fmaf(p.w, q2[j], fmaf(p.z, q1[j], fmaf(p.y, q0[j], p.x)));
            mn[j] = fminf(mn[j], t);
        }
    }

    float* dst = part + ((size_t)b * NCHUNK + chunk) * L2;
    #pragma unroll
    for (int j = 0; j < MPT; ++j) {
        const int m = mbase + j * BLK;
        if (m < L2) {
            const float qq = fmaf(q0[j], q0[j], fmaf(q1[j], q1[j], q2[j] * q2[j]));
            dst[m] = mn[j] + qq;
        }
    }
}

// One block per b: min across chunks, sqrt, fixed-order reduce, write out[b].
__global__ void __launch_bounds__(RBLK)
k_reduce(const float* __restrict__ part, const float* __restrict__ res,
         float* __restrict__ out, int L2) {
    const int b = blockIdx.x;

    float sum = 0.0f;
    for (int m = threadIdx.x; m < L2; m += RBLK) {
        float v = FLT_BIG;
        #pragma unroll
        for (int c = 0; c < NCHUNK; ++c)
            v = fminf(v, part[((size_t)b * NCHUNK + c) * L2 + m]);
        sum += sqrtf(fmaxf(v, 0.0f));
    }

    // Wave-level shuffle reduce (fixed order), then LDS across 16 waves.
    #pragma unroll
    for (int s = 32; s > 0; s >>= 1)
        sum += __shfl_down(sum, s, 64);

    __shared__ float wred[RBLK / 64];
    const int wid = threadIdx.x >> 6;
    const int lane = threadIdx.x & 63;
    if (lane == 0) wred[wid] = sum;
    __syncthreads();

    if (threadIdx.x == 0) {
        float tot = 0.0f;
        #pragma unroll
        for (int w = 0; w < RBLK / 64; ++w) tot += wred[w];
        out[b] = tot * res[0] / (float)L2;
    }
}

extern "C" void kernel_launch(void* const* d_in, const int* in_sizes, int n_in,
                              void* d_out, int out_size, void* d_ws, size_t ws_size,
                              hipStream_t stream) {
    const float* c1  = (const float*)d_in[0];
    const float* c2  = (const float*)d_in[1];
    const float* res = (const float*)d_in[2];
    float* out = (float*)d_out;

    const int B = out_size;                 // 4
    const int D = 3;
    const int L1 = in_sizes[0] / (B * D);   // 4096
    const int L2 = in_sizes[1] / (B * D);   // 4096

    float* part = (float*)d_ws;             // B*NCHUNK*L2 floats (2 MiB)

    const int CL = (L1 + NCHUNK - 1) / NCHUNK;        // 128
    dim3 g1((L2 + BLK * MPT - 1) / (BLK * MPT), NCHUNK, B);
    k_min<<<g1, BLK, 0, stream>>>(c1, c2, part, L1, L2, CL);

    k_reduce<<<B, RBLK, 0, stream>>>(part, res, out, L2);
}